// Round 15
// baseline (285.884 us; speedup 1.0000x reference)
//
#include <hip/hip_runtime.h>
#include <stdint.h>

#define BATCH 8
#define LSEQ 16384
#define HDIM 128
#define KSZ 65
#define PADW 32
#define LH (LSEQ*HDIM)
#define TL 256
#define NROWS (TL + 2*PADW)     // 320 staged Q rows
#define LBLKS (LSEQ/TL)         // 64
#define EXP_SHIFT 20.0f

#define WS_WBF_OFF 4096         // bf16 W-fragments start here; gsum f32[1024] at offset 0

typedef __attribute__((ext_vector_type(8))) short bf16x8;
typedef __attribute__((ext_vector_type(4))) short bf16x4;
typedef __attribute__((ext_vector_type(16))) float f32x16;

__device__ __forceinline__ unsigned short f2bf(float f) {
  unsigned int u = __float_as_uint(f);
  return (unsigned short)((u + 0x7FFFu + ((u >> 16) & 1u)) >> 16);  // RNE
}

// ---------------- K0: W [o][i][k] f32 -> per-(tap,wc,ks) fragment-ordered bf16 ----------------
// Wbf[k][wc][ks][kk2][hi2][l31][e] : the 4KB chunk (k,wc,ks) is contiguous and laid out
// exactly like a wave's private LDS buffer (global_load_lds stages it linearly).
// o = wc*32 + l31 ; i = ks*64 + kk2*16 + hi2*8 + e.
__global__ __launch_bounds__(256) void wcvt_kernel(const float* __restrict__ W,
                                                   unsigned short* __restrict__ Wbf) {
  __shared__ float lw[KSZ*HDIM];
  const int o = blockIdx.x;
  const float* src = W + (size_t)o * (HDIM*KSZ);
  for (int t = threadIdx.x; t < HDIM*KSZ; t += 256) lw[t] = src[t];
  __syncthreads();
  const int wc_ = o >> 5;
  const int l31 = o & 31;
  for (int idx = threadIdx.x; idx < KSZ*HDIM; idx += 256) {
    const int k = idx >> 7;      // 0..64
    const int i = idx & 127;
    const int ks_ = i >> 6;
    const int kk2 = (i >> 4) & 3;
    const int hi2 = (i >> 3) & 1;
    const int e   = i & 7;
    const size_t dst = (size_t)k*16384 + wc_*4096 + ks_*2048 + kk2*512 + hi2*256 + l31*8 + e;
    Wbf[dst] = f2bf(lw[i*KSZ + k]);
  }
}

// ---------------- K1: conv GEMM, wave-private W dbuf, ZERO barriers in tap loop ----------------
__global__ __launch_bounds__(512, 2) void conv_gate_kernel(
    const float* __restrict__ Qm, const float* __restrict__ Km,
    const unsigned short* __restrict__ Wfrag,
    float* __restrict__ Eout, float* __restrict__ gsum) {

  __shared__ __align__(16) char smem[147456];   // Qs 80K | 8 x (2 x 4KB) wave-private W
  unsigned short* Qs = (unsigned short*)smem;

  const int tid  = threadIdx.x;
  const int lane = tid & 63;
  const int w    = tid >> 6;    // 0..7
  const int ks   = w & 1;       // K-half: input channels [ks*64, ks*64+64)
  const int wc   = w >> 1;      // 0..3 : 32-col band
  const int l31  = lane & 31;
  const int hi2  = lane >> 5;   // 0..1

  const int bx = blockIdx.x;
  const int b  = bx >> 6;
  const int l0 = (bx & 63) << 8;   // * TL

  // ---- stage Q rows [l0-32, l0+TL+32) as swizzled bf16 ----
  {
    const int r0 = tid >> 5;            // 0..15
    const int c4 = (tid & 31) << 2;     // 0..124 step 4
    const float* qbase = Qm + (size_t)b*LH + c4;
#pragma unroll
    for (int it = 0; it < NROWS/16; ++it) {
      const int r = it*16 + r0;
      const int grow = l0 - PADW + r;
      bf16x4 pk = {0, 0, 0, 0};
      if (grow >= 0 && grow < LSEQ) {
        const float4 qv = *(const float4*)(qbase + (size_t)grow*HDIM);
        pk[0] = (short)f2bf(qv.x); pk[1] = (short)f2bf(qv.y);
        pk[2] = (short)f2bf(qv.z); pk[3] = (short)f2bf(qv.w);
      }
      *(bf16x4*)(&Qs[r*HDIM + (c4 ^ ((r & 15) << 3))]) = pk;
    }
  }

  // wave-private W slot (8 KB = 2 buffers x 4 KB) and its global source base
  char* wslot = smem + 81920 + w*8192;
  const char* gW = (const char*)Wfrag + wc*8192 + ks*4096;   // + k*32768 + j*1024

  // prologue: stage tap 0 -> buf 0 (4 x 1KB, linear dest, own loads only)
#pragma unroll
  for (int j = 0; j < 4; ++j)
    __builtin_amdgcn_global_load_lds(
        (const __attribute__((address_space(1))) unsigned int*)(gW + j*1024 + lane*16),
        (__attribute__((address_space(3))) unsigned int*)(wslot + j*1024 + lane*16 - lane*16 + j*0 + (lane*16)), 16, 0, 0);
  // (dest arg must be wave-uniform base + lane*16 implicit; rewrite correctly below)

  f32x16 acc[8] = {};

  __syncthreads();   // Q staged + prologue stage drained (implicit vmcnt(0) lgkmcnt(0))

  const int rbase = l31;               // A row base offset (per lane)

  for (int k = 0; k < KSZ; ++k) {
    const int cur = k & 1;
    // own stage loads of tap k landed (issued a full tap ago; L2-fast) — NO barrier
    asm volatile("s_waitcnt vmcnt(0)" ::: "memory");
    if (k < KSZ-1) {
      const char* gs = gW + (size_t)(k+1)*32768;
      char* ld = wslot + (cur^1)*4096;
#pragma unroll
      for (int j = 0; j < 4; ++j)
        __builtin_amdgcn_global_load_lds(
            (const __attribute__((address_space(1))) unsigned int*)(gs + j*1024 + lane*16),
            (__attribute__((address_space(3))) unsigned int*)(ld + j*1024),
            16, 0, 0);
    }

    const unsigned short* bslot = (const unsigned short*)(wslot + cur*4096);
    const int rb = k + rbase;                   // rows rb + 32m, m=0..7
    const int xa = (rb & 15) << 3;              // same (r&15) for all m

#pragma unroll
    for (int kk = 0; kk < 4; ++kk) {
      const int i0 = (ks*64 + kk*16 + hi2*8) ^ xa;
      const unsigned short* ar = &Qs[rb*HDIM + i0];     // + m*4096 elems (const offsets)
      const bf16x8 B = *(const bf16x8*)(bslot + kk*512 + hi2*256 + l31*8);
      const bf16x8 A0 = *(const bf16x8*)(ar);
      const bf16x8 A1 = *(const bf16x8*)(ar + 1*4096);
      const bf16x8 A2 = *(const bf16x8*)(ar + 2*4096);
      const bf16x8 A3 = *(const bf16x8*)(ar + 3*4096);
      const bf16x8 A4 = *(const bf16x8*)(ar + 4*4096);
      const bf16x8 A5 = *(const bf16x8*)(ar + 5*4096);
      const bf16x8 A6 = *(const bf16x8*)(ar + 6*4096);
      const bf16x8 A7 = *(const bf16x8*)(ar + 7*4096);
      acc[0] = __builtin_amdgcn_mfma_f32_32x32x16_bf16(A0, B, acc[0], 0, 0, 0);
      acc[1] = __builtin_amdgcn_mfma_f32_32x32x16_bf16(A1, B, acc[1], 0, 0, 0);
      acc[2] = __builtin_amdgcn_mfma_f32_32x32x16_bf16(A2, B, acc[2], 0, 0, 0);
      acc[3] = __builtin_amdgcn_mfma_f32_32x32x16_bf16(A3, B, acc[3], 0, 0, 0);
      acc[4] = __builtin_amdgcn_mfma_f32_32x32x16_bf16(A4, B, acc[4], 0, 0, 0);
      acc[5] = __builtin_amdgcn_mfma_f32_32x32x16_bf16(A5, B, acc[5], 0, 0, 0);
      acc[6] = __builtin_amdgcn_mfma_f32_32x32x16_bf16(A6, B, acc[6], 0, 0, 0);
      acc[7] = __builtin_amdgcn_mfma_f32_32x32x16_bf16(A7, B, acc[7], 0, 0, 0);
    }
  }

  // ---- K-split reduction: ks=1 partial -> LDS -> ks=0 adds ----
  __syncthreads();                            // all waves done with Qs + W slots
  float* red = (float*)smem;                  // 4 regions x 32 KB (per wc)
  float* reg = red + wc*8192 + lane*4;
  if (ks == 1) {
#pragma unroll
    for (int q4 = 0; q4 < 32; ++q4) {
      const int m = q4 >> 2, r4 = (q4 & 3) << 2;
      float4 v;
      v.x = acc[m][r4];   v.y = acc[m][r4+1];
      v.z = acc[m][r4+2]; v.w = acc[m][r4+3];
      *(float4*)(reg + q4*256) = v;
    }
  }
  __syncthreads();

  if (ks == 0) {
#pragma unroll
    for (int q4 = 0; q4 < 32; ++q4) {
      const int m = q4 >> 2, r4 = (q4 & 3) << 2;
      const float4 v = *(const float4*)(reg + q4*256);
      acc[m][r4]   += v.x; acc[m][r4+1] += v.y;
      acc[m][r4+2] += v.z; acc[m][r4+3] += v.w;
    }
    // ---- epilogue: gate by K, exp-shift, store E, per-column partial sum ----
    float psum = 0.f;
#pragma unroll
    for (int m = 0; m < 8; ++m) {
#pragma unroll
      for (int r = 0; r < 16; ++r) {
        const int row = m*32 + (r & 3) + 8*(r >> 2) + 4*hi2;          // C/D (m74/m101)
        const size_t gb = (size_t)b*LH + (size_t)(l0 + row)*HDIM + wc*32 + l31;
        const float s = acc[m][r] * Km[gb];                            // col = lane&31
        const float e = __expf(s - EXP_SHIFT);
        Eout[gb] = e;
        psum += e;
      }
    }
    psum += __shfl_xor(psum, 32);            // fold hi2 halves (same column)
    if (hi2 == 0)
      atomicAdd(&gsum[b*HDIM + wc*32 + l31], psum);
  }
}

// ---------------- K2: Z = E * V / gsum (in place on d_out) ----------------
__global__ __launch_bounds__(256) void finalize_kernel(float* __restrict__ out,
                                                       const float* __restrict__ V,
                                                       const float* __restrict__ gsum) {
  const int total4 = (BATCH*LH) >> 2;
  const int stride = gridDim.x * blockDim.x;
  for (int f = blockIdx.x*blockDim.x + threadIdx.x; f < total4; f += stride) {
    const float4 e = ((const float4*)out)[f];
    const float4 v = ((const float4*)V)[f];
    const int e0 = f << 2;
    const float* gs = gsum + ((e0 >> 21) << 7) + (e0 & 127);   // b*128 + h0
    float4 z;
    z.x = e.x * v.x / gs[0];
    z.y = e.y * v.y / gs[1];
    z.z = e.z * v.z / gs[2];
    z.w = e.w * v.w / gs[3];
    ((float4*)out)[f] = z;
  }
}

extern "C" void kernel_launch(void* const* d_in, const int* in_sizes, int n_in,
                              void* d_out, int out_size, void* d_ws, size_t ws_size,
                              hipStream_t stream) {
  (void)in_sizes; (void)n_in; (void)out_size; (void)ws_size;
  const float* Q = (const float*)d_in[0];
  const float* K = (const float*)d_in[1];
  const float* V = (const float*)d_in[2];
  const float* W = (const float*)d_in[3];
  float* out  = (float*)d_out;
  float* gsum = (float*)d_ws;
  unsigned short* Wbf = (unsigned short*)((char*)d_ws + WS_WBF_OFF);

  hipMemsetAsync(d_ws, 0, BATCH*HDIM*sizeof(float), stream);          // gsum = 0
  wcvt_kernel<<<HDIM, 256, 0, stream>>>(W, Wbf);                      // W -> per-(k,wc,ks) frag order
  conv_gate_kernel<<<BATCH*LBLKS, 512, 0, stream>>>(Q, K, Wbf, out, gsum);
  finalize_kernel<<<2048, 256, 0, stream>>>(out, V, gsum);
}